// Round 15
// baseline (208.235 us; speedup 1.0000x reference)
//
#include <hip/hip_runtime.h>
#include <hip/hip_bf16.h>

typedef __hip_bfloat16 bf16;
typedef unsigned short u16;
typedef unsigned int u32;
typedef __attribute__((ext_vector_type(8))) short short8v;
typedef __attribute__((ext_vector_type(4))) float f32x4;

// ---------------- geometry ----------------
// 12 scan problems: g = dir*2+b for dir 0..3 (L=4096), g = 8.. (L=1024)
// T_TOT rows = 36864. Chunk Lc=32 -> 1152 chunks.
// k_front: FUSED in_proj(MFMA) + conv + x_proj(MFMA) + dt + half-split chunk scan; 1152 blocks.
// k_outproj: fused scan3 + GEMM. GN stats: per-block partials (plain stores), reduced in consumers.

// ---------------- workspace layout (float units) ----------------
#define XCB_OFF   0u            /* bf16 [36864][128] conv-x */
#define DTB_OFF   2359296u      /* bf16 [36864][128] dt */
#define BCB_OFF   4718592u      /* bf16 [36864][32]  B(16) C(16) */
#define CHA_OFF   5308416u      /* f32 [1152][2048] chunk a-products */
#define CHH_OFF   7667712u      /* f32 [1152][2048] chunk h / carry-in */
#define XZ_OFF    10027008u     /* bf16 [36864][256]; only z-half (cols 128..255) written/read */
#define UFS_OFF   14745600u     /* f32 (B,L,64) full-res */
#define UFD_OFF   15269888u     /* f32 (B,1024,64) downsampled */
#define XS_OFF    15400960u     /* f32 NHWC [2][4096][64] */
#define XTG_OFF   15925248u
#define XTD_OFF   16449536u     /* f32 NHWC [2][1024][64] */
#define XSB_OFF   16580608u     /* bf16 NHWC copy of XS */
#define WT4_OFF   16842752u     /* bf16 [4][9][64][64] conv weights frag order */
#define STATS_OFF 16916480u     /* legacy, unused */
#define FLAG_OFF  16916736u     /* [0] dtype flag, [1] A-pattern flag */
#define PRM_OFF   16916752u     /* bf16 staging, 348864 entries */
#define PART_OFF  17091184u     /* f32 [4 stages][256 blocks][8] GN partials */
/* conv-branch aliases in dead XCB/DTB region (after k_outproj) */
#define CV0_OFF   0u
#define CV1_OFF   524288u
#define A1B_OFF   1048576u
#define A2B_OFF   1310720u
#define PWB_OFF   1572864u

__device__ __forceinline__ float bits2f(u16 v){
  u32 u = ((u32)v) << 16; float f; __builtin_memcpy(&f, &u, 4); return f;
}
__device__ __forceinline__ float b2f(bf16 v){ return __bfloat162float(v); }
__device__ __forceinline__ u16 f2bu(float f){ bf16 h = __float2bfloat16(f); u16 b; __builtin_memcpy(&b, &h, 2); return b; }
__device__ __forceinline__ float silu_f(float x){ return x / (1.f + __expf(-x)); }
__device__ __forceinline__ float softplus_f(float x){ return fmaxf(x, 0.f) + log1pf(__expf(-fabsf(x))); }
__device__ __forceinline__ float gelu_f(float x){ return 0.5f * x * (1.f + erff(x * 0.70710678118654752f)); }
__device__ __forceinline__ short8v zero8(){ short8v z = {0,0,0,0,0,0,0,0}; return z; }
__device__ __forceinline__ void up2(u32 w, float& a, float& b){
  a = bits2f((u16)(w & 0xffffu)); b = bits2f((u16)(w >> 16));
}
// aa[s] = r^(s+1), depth-4 multiply tree
__device__ __forceinline__ void powchain(float r, float* aa){
  aa[0]=r; aa[1]=r*r; aa[2]=aa[1]*r; aa[3]=aa[1]*aa[1];
  aa[4]=aa[3]*r; aa[5]=aa[3]*aa[1]; aa[6]=aa[3]*aa[2]; aa[7]=aa[3]*aa[3];
  aa[8]=aa[7]*r; aa[9]=aa[7]*aa[1]; aa[10]=aa[7]*aa[2]; aa[11]=aa[7]*aa[3];
  aa[12]=aa[7]*aa[4]; aa[13]=aa[7]*aa[5]; aa[14]=aa[7]*aa[6]; aa[15]=aa[7]*aa[7];
}

struct P29 { const void* p[29]; };

__constant__ int PREF[30] = {0, 98304, 101376, 102144, 129792, 132864, 133632,
  145920, 146688, 195840, 196416, 196480, 200576, 200640, 237504, 237568,
  237632, 237696, 274560, 274624, 274688, 274752, 311616, 311680, 311744,
  311808, 348672, 348736, 348800, 348864};

__constant__ float LOGT[16] = {0.0f, 0.6931472f, 1.0986123f, 1.3862944f,
  1.6094379f, 1.7917595f, 1.9459101f, 2.0794415f, 2.1972246f, 2.3025851f,
  2.3978953f, 2.4849067f, 2.5649493f, 2.6390573f, 2.7080502f, 2.7725887f};

// ---------------- k_detect: dtype flag + A_log pattern flag ----------------
__global__ void k_detect(const void* __restrict__ xraw, const void* __restrict__ araw,
                         float* __restrict__ ws){
  __shared__ int cnt_s, bad_s;
  int tid = threadIdx.x;
  if (tid == 0){ cnt_s = 0; bad_s = 0; }
  __syncthreads();
  const u16* p = (const u16*)xraw;
  int c = 0;
  for (int i = tid; i < 4096; i += 256){
    int e = (p[i] >> 7) & 0xFF;
    if (e >= 0x77 && e <= 0x87) c++;
  }
  atomicAdd(&cnt_s, c);
  __syncthreads();
  int flag = (cnt_s > 3500) ? 0 : 1;   // 1 -> f32 inputs, 0 -> bf16 inputs
  int bad = 0;
  for (int i = tid; i < 12288; i += 256){
    float v = flag ? ((const float*)araw)[i] : b2f(((const bf16*)araw)[i]);
    if (fabsf(v - LOGT[i & 15]) > 0.02f) bad = 1;
  }
  if (bad) atomicAdd(&bad_s, 1);
  __syncthreads();
  if (tid == 0){
    ((int*)(ws + FLAG_OFF))[0] = flag;
    ((int*)(ws + FLAG_OFF))[1] = (bad_s == 0) ? 1 : 0;
  }
}

// ---------------- k_setup: fused cvt + prep + wprep ----------------
__global__ __launch_bounds__(256) void k_setup(P29 ptrs, const void* __restrict__ xraw,
                                               float* __restrict__ ws){
  int bid = blockIdx.x, tid = threadIdx.x;
  int flag = *(const int*)(ws + FLAG_OFF);
  const float* xf = (const float*)xraw;
  const bf16*  xb = (const bf16*)xraw;
  if (bid < 2560){
    int i = bid * 256 + tid;
    if (i < 524288){
      int b = i >> 18, rem = i & 262143, l = rem >> 6, d = rem & 63;
      size_t idx = (size_t)b*262144 + d*4096 + l;
      ws[UFS_OFF + i] = flag ? xf[idx] : b2f(xb[idx]);
    } else if (i < 655360){
      int j = i - 524288;
      int b = j >> 16, rem = j & 65535, l = rem >> 6, d = rem & 63;
      int i2 = l >> 5, j2 = l & 31;
      size_t base = (size_t)b*262144 + d*4096 + (i2*2)*64 + j2*2;
      float v0, v1, v2, v3;
      if (flag){ v0 = xf[base]; v1 = xf[base+1]; v2 = xf[base+64]; v3 = xf[base+65]; }
      else     { v0 = b2f(xb[base]); v1 = b2f(xb[base+1]); v2 = b2f(xb[base+64]); v3 = b2f(xb[base+65]); }
      ws[UFD_OFF + j] = 0.25f * (v0 + v1 + v2 + v3);
    }
  } else if (bid < 3923){
    int i = (bid - 2560) * 256 + tid;
    if (i < 348864){
      int t = 0;
      #pragma unroll 1
      while (i >= PREF[t + 1]) ++t;
      int off = i - PREF[t];
      float v = flag ? ((const float*)ptrs.p[t])[off]
                     : b2f(((const bf16*)ptrs.p[t])[off]);
      ((bf16*)(ws + PRM_OFF))[i] = __float2bfloat16(v);
    }
  } else {
    int i = (bid - 3923) * 256 + tid;
    if (i < 147456){
      int conv = i / 36864, r = i - conv * 36864;
      int tap = r >> 12, co = (r >> 6) & 63, ci = r & 63;
      const int SRC[4] = {13, 17, 21, 25};
      const void* sp_ = ptrs.p[SRC[conv]];
      size_t off = (size_t)co * 576 + ci * 9 + tap;
      float v = flag ? ((const float*)sp_)[off] : b2f(((const bf16*)sp_)[off]);
      ((bf16*)(ws + WT4_OFF))[i] = __float2bfloat16(v);
    }
  }
}

__device__ __forceinline__ void chunk_map(int bid, int& g, int& c0){
  if (bid < 1024){ g = bid >> 7; c0 = bid & 127; }
  else { int r = bid - 1024; g = 8 + (r >> 5); c0 = r & 31; }
}

// ---------------- k_front: FUSED in_proj(MFMA) + conv+silu + x_proj(MFMA) + dt + chunk scan ------
// 1152 blocks x 256 threads. Computes its own XZ tile (x->LDS, z->global), then as before.
__global__ __launch_bounds__(256) void k_front(float* __restrict__ ws, const bf16* __restrict__ in_w,
        const bf16* __restrict__ xproj_w, const bf16* __restrict__ dt_w, const bf16* __restrict__ dt_b,
        const bf16* __restrict__ conv_w, const bf16* __restrict__ conv_b, const bf16* __restrict__ A_log){
  __shared__ __align__(16) u32 pool[1280];      // u_s u16[35][72] (5040B) / xp_s f32[32][40] (5120B)
  __shared__ __align__(16) u16 x_s[35 * 132];   // bf16 x rows t0-3..t0+31
  __shared__ __align__(16) u16 xc_s[32][136];
  __shared__ __align__(16) u32 blob[4352];      // xw_s u16[48][136] (13056B) / cmb f32[4352]
  u16* u_s = (u16*)pool;
  float* xp_s = (float*)pool;
  u16* xw_s = (u16*)blob;
  float* cmb = (float*)blob;                    // P0 at [c*17+s], H0 at [2176 + c*17+s]

  int g, c0; chunk_map(blockIdx.x, g, c0);
  int dir = (g < 8) ? (g >> 1) : 4 + ((g - 8) >> 1);
  int bb  = (g < 8) ? (g & 1) : ((g - 8) & 1);
  int rev = dir & 1;
  int L   = (g < 8) ? 4096 : 1024;
  int grow0 = (g < 8) ? g * 4096 : 32768 + (g - 8) * 1024;
  int t0 = c0 << 5;
  int crow = ((g < 8) ? g * 128 : 1024 + (g - 8) * 32) + c0;
  const float* U = (g < 8) ? (ws + UFS_OFF + (size_t)bb * 262144)
                           : (ws + UFD_OFF + (size_t)bb * 65536);
  int tid = threadIdx.x;

  // stage U rows [t0-3, t0+32) as bf16 + xproj weights
  for (int e = tid; e < 2240; e += 256){
    int lr = e >> 6, k = e & 63;
    int gt = t0 - 3 + lr;
    float v = 0.f;
    if (gt >= 0){
      int l = rev ? (L - 1 - gt) : gt;
      v = U[(size_t)l * 64 + k];
    }
    u_s[lr * 72 + k] = f2bu(v);
  }
  const u16* xw = (const u16*)xproj_w + (size_t)dir * 4608;
  for (int e = tid; e < 6144; e += 256){
    int m = e >> 7, col = e & 127;
    xw_s[m * 136 + col] = (m < 36) ? xw[m * 128 + col] : (u16)0;
  }
  __syncthreads();

  // phase 0: in_proj tile via MFMA: rows t0..t0+31 (x -> x_s LDS, z -> XZ global);
  //          halo x rows t0-3..t0-1 via VALU dots
  {
    int w = tid >> 6, lane = tid & 63;
    int l15 = lane & 15, ko = lane >> 4;
    short8v Au[2][2];
    #pragma unroll
    for (int mt = 0; mt < 2; ++mt)
      #pragma unroll
      for (int kk = 0; kk < 2; ++kk)
        Au[mt][kk] = *(const short8v*)(u_s + (size_t)(3 + mt * 16 + l15) * 72 + kk * 32 + ko * 8);
    const u16* wg = (const u16*)in_w + (size_t)dir * 16384;
    u16* XZu = (u16*)(ws + XZ_OFF);
    #pragma unroll
    for (int nq = 0; nq < 4; ++nq){
      int nt = w * 4 + nq;
      int c = nt * 16 + l15;
      short8v B0 = *(const short8v*)(wg + (size_t)c * 64 + ko * 8);
      short8v B1 = *(const short8v*)(wg + (size_t)c * 64 + 32 + ko * 8);
      #pragma unroll
      for (int mt = 0; mt < 2; ++mt){
        f32x4 acc = {0.f, 0.f, 0.f, 0.f};
        acc = __builtin_amdgcn_mfma_f32_16x16x32_bf16(Au[mt][0], B0, acc, 0, 0, 0);
        acc = __builtin_amdgcn_mfma_f32_16x16x32_bf16(Au[mt][1], B1, acc, 0, 0, 0);
        #pragma unroll
        for (int reg = 0; reg < 4; ++reg){
          int t = mt * 16 + ko * 4 + reg;
          u16 v = f2bu(acc[reg]);
          if (c < 128) x_s[(3 + t) * 132 + c] = v;
          else XZu[(size_t)(grow0 + t0 + t) * 256 + c] = v;
        }
      }
    }
    // halo dots (384 tasks: 3 rows x 128 cols)
    for (int task = tid; task < 384; task += 256){
      int lr = task >> 7, cc = task & 127;
      int gt = t0 - 3 + lr;
      float acc = 0.f;
      if (gt >= 0){
        const u16* wr = wg + (size_t)cc * 64;
        #pragma unroll
        for (int j = 0; j < 8; ++j){
          short8v wv = *(const short8v*)(wr + j * 8);
          #pragma unroll
          for (int q = 0; q < 8; ++q)
            acc = fmaf(bits2f(u_s[lr * 72 + j * 8 + q]), bits2f((u16)wv[q]), acc);
        }
      }
      x_s[lr * 132 + cc] = f2bu(acc);
    }
  }
  __syncthreads();

  int c = tid & 127, hf = tid >> 7;
  int rb = hf * 16;
  // phase 1: causal conv + silu (reads x_s)
  {
    const u16* cwp = (const u16*)conv_w + (size_t)dir * 512 + c * 4;
    uint2 cw2 = *(const uint2*)cwp;
    float cw0, cw1, cw2f, cw3;
    up2(cw2.x, cw0, cw1); up2(cw2.y, cw2f, cw3);
    float cb = b2f(conv_b[dir * 128 + c]);
    float xm3 = bits2f(x_s[rb * 132 + c]);
    float xm2 = bits2f(x_s[(rb + 1) * 132 + c]);
    float xm1 = bits2f(x_s[(rb + 2) * 132 + c]);
    u16* XCBu = (u16*)(ws + XCB_OFF);
    #pragma unroll 4
    for (int t = 0; t < 16; ++t){
      float xcur = bits2f(x_s[(rb + t + 3) * 132 + c]);
      float s = cb + cw0 * xm3 + cw1 * xm2 + cw2f * xm1 + cw3 * xcur;
      u16 xbv = f2bu(silu_f(s));
      xm3 = xm2; xm2 = xm1; xm1 = xcur;
      xc_s[rb + t][c] = xbv;
      XCBu[(size_t)(grow0 + t0 + rb + t) * 128 + c] = xbv;
    }
  }
  __syncthreads();

  // phase 2: x_proj via MFMA: C[32][36] = xc[32][128] @ xw^T (xp_s aliases u_s pool)
  {
    int w = tid >> 6, lane = tid & 63;
    int l15 = lane & 15, ko = lane >> 4;
    for (int task = w; task < 6; task += 4){
      int mt = task & 1, nt = task >> 1;
      f32x4 acc = {0.f, 0.f, 0.f, 0.f};
      #pragma unroll
      for (int kk = 0; kk < 4; ++kk){
        short8v Afr = *(const short8v*)&xc_s[mt * 16 + l15][kk * 32 + ko * 8];
        short8v Bfr = *(const short8v*)(xw_s + (size_t)(nt * 16 + l15) * 136 + kk * 32 + ko * 8);
        acc = __builtin_amdgcn_mfma_f32_16x16x32_bf16(Afr, Bfr, acc, 0, 0, 0);
      }
      int j = nt * 16 + l15;
      if (j < 36){
        #pragma unroll
        for (int reg = 0; reg < 4; ++reg){
          int t = mt * 16 + ko * 4 + reg;
          xp_s[t * 40 + j] = acc[reg];
        }
      }
    }
  }
  __syncthreads();

  // phase 2.5: round B/C to bf16 + write BCB
  {
    u16* BCBu = (u16*)(ws + BCB_OFF);
    for (int e = tid; e < 1024; e += 256){
      int t = e >> 5, v = e & 31;
      float val = xp_s[t * 40 + 4 + v];
      u16 r = f2bu(val);
      xp_s[t * 40 + 4 + v] = bits2f(r);
      BCBu[(size_t)(grow0 + t0 + t) * 32 + v] = r;
    }
  }
  __syncthreads();

  // phase 3: dt + 16-step local scan per half + combine
  {
    int apat = ((const int*)(ws + FLAG_OFF))[1];
    float A[16];
    const u16* ap = (const u16*)A_log + (size_t)dir * 2048 + c * 16;
    #pragma unroll
    for (int s = 0; s < 16; ++s) A[s] = -__expf(bits2f(ap[s]));
    const u16* dwp = (const u16*)dt_w + (size_t)dir * 512 + c * 4;
    uint2 dw2 = *(const uint2*)dwp;
    float d0, d1, d2, d3;
    up2(dw2.x, d0, d1); up2(dw2.y, d2, d3);
    float db = b2f(dt_b[dir * 128 + c]);
    u16* DTBu = (u16*)(ws + DTB_OFF);
    float hh[16], p[16];
    #pragma unroll
    for (int s = 0; s < 16; ++s){ hh[s] = 0.f; p[s] = 1.f; }
    float dtsum = 0.f;
    #pragma unroll 2
    for (int t = 0; t < 16; ++t){
      float4 xp4 = *(const float4*)&xp_s[(rb + t) * 40];
      float dtv = softplus_f(db + d0 * xp4.x + d1 * xp4.y + d2 * xp4.z + d3 * xp4.w);
      u16 dtb16 = f2bu(dtv);
      DTBu[(size_t)(grow0 + t0 + rb + t) * 128 + c] = dtb16;
      float dtu = bits2f(dtb16);
      float xcv = bits2f(xc_s[rb + t][c]);
      float dx = dtu * xcv;
      float aa[16];
      if (apat){
        dtsum += dtu;
        powchain(__expf(-dtu), aa);
      } else {
        #pragma unroll
        for (int s = 0; s < 16; ++s) aa[s] = __expf(dtu * A[s]);
        #pragma unroll
        for (int s = 0; s < 16; ++s) p[s] *= aa[s];
      }
      #pragma unroll
      for (int s = 0; s < 16; ++s)
        hh[s] = fmaf(aa[s], hh[s], dx * xp_s[(rb + t) * 40 + 4 + s]);
    }
    if (apat) powchain(__expf(-dtsum), p);
    if (hf == 0){
      #pragma unroll
      for (int s = 0; s < 16; ++s){
        cmb[c * 17 + s] = p[s];
        cmb[2176 + c * 17 + s] = hh[s];
      }
    }
    __syncthreads();
    if (hf == 1){
      float ca[16], ch[16];
      #pragma unroll
      for (int s = 0; s < 16; ++s){
        float P0 = cmb[c * 17 + s];
        float H0 = cmb[2176 + c * 17 + s];
        ca[s] = P0 * p[s];
        ch[s] = fmaf(p[s], H0, hh[s]);
      }
      float* CA = ws + CHA_OFF + (size_t)crow * 2048 + c * 16;
      float* CH = ws + CHH_OFF + (size_t)crow * 2048 + c * 16;
      #pragma unroll
      for (int q = 0; q < 4; ++q){
        *(float4*)(CA + q * 4) = make_float4(ca[q*4], ca[q*4+1], ca[q*4+2], ca[q*4+3]);
        *(float4*)(CH + q * 4) = make_float4(ch[q*4], ch[q*4+1], ch[q*4+2], ch[q*4+3]);
      }
    }
  }
}

// ---------------- k_scan2: sequential carry across chunks (unrolled x8) ----------------
__global__ __launch_bounds__(256) void k_scan2(float* __restrict__ ws){
  int id = blockIdx.x * 256 + threadIdx.x;
  int gi = id >> 11, dsl = id & 2047;
  int nc = (gi < 8) ? 128 : 32;
  int cb = (gi < 8) ? gi * 128 : 1024 + (gi - 8) * 32;
  float* CA = ws + CHA_OFF; float* CH = ws + CHH_OFF;
  float hprev = 0.f;
  for (int ch = 0; ch < nc; ch += 8){
    size_t i0 = (size_t)(cb + ch) * 2048 + dsl;
    float a[8], hv[8];
    #pragma unroll
    for (int j = 0; j < 8; ++j){
      a[j] = CA[i0 + (size_t)j * 2048];
      hv[j] = CH[i0 + (size_t)j * 2048];
    }
    #pragma unroll
    for (int j = 0; j < 8; ++j){
      CH[i0 + (size_t)j * 2048] = hprev;
      hprev = fmaf(a[j], hprev, hv[j]);
    }
  }
}

// ---------------- k_outproj: FUSED scan3 + MFMA GEMM ------------------------------------------
__global__ __launch_bounds__(256) void k_outproj(float* __restrict__ ws, const bf16* __restrict__ out_w,
        const bf16* __restrict__ A_log, const bf16* __restrict__ Dp){
  __shared__ __align__(16) u16 yf_s[32][132];
  __shared__ __align__(16) u16 yb_s[32][132];
  int bid = blockIdx.x;
  int pair, b, tile, L;
  if (bid < 512){ pair = bid >> 8; b = (bid >> 7) & 1; tile = bid & 127; L = 4096; }
  else { int r = bid - 512; pair = 2; b = r >> 5; tile = r & 31; L = 1024; }
  int l0 = tile * 32;
  int ncht = L >> 5;
  int df = pair * 2, db_ = df + 1;
  int gf = (pair < 2) ? df * 2 + b : 8 + b;
  int gb = (pair < 2) ? db_ * 2 + b : 10 + b;
  int rowf0 = (gf < 8) ? gf * 4096 : 32768 + (gf - 8) * 1024;
  int rowb0 = (gb < 8) ? gb * 4096 : 32768 + (gb - 8) * 1024;
  int tid = threadIdx.x;

  {
    int half = tid >> 7, d = tid & 127;
    int gS = half ? gb : gf;
    int dirS = (gS < 8) ? (gS >> 1) : 4 + ((gS - 8) >> 1);
    int rowS = half ? (rowb0 + (L - 32 - l0)) : (rowf0 + l0);
    int cbaseS = (gS < 8) ? gS * 128 : 1024 + (gS - 8) * 32;
    int crowS = cbaseS + (half ? (ncht - 1 - tile) : tile);
    int apat = ((const int*)(ws + FLAG_OFF))[1];
    float A[16];
    const u16* ap = (const u16*)A_log + (size_t)dirS * 2048 + d * 16;
    #pragma unroll
    for (int s = 0; s < 16; ++s) A[s] = -__expf(bits2f(ap[s]));
    float h[16];
    const float* CH = ws + CHH_OFF + (size_t)crowS * 2048 + d * 16;
    #pragma unroll
    for (int s = 0; s < 16; ++s) h[s] = CH[s];
    float Dv = b2f(Dp[dirS * 128 + d]);
    const u16* XCBu = (const u16*)(ws + XCB_OFF);
    const u16* DTBu = (const u16*)(ws + DTB_OFF);
    const u16* BCBu = (const u16*)(ws + BCB_OFF);
    const u16* XZu  = (const u16*)(ws + XZ_OFF);
    #pragma unroll 2
    for (int t = 0; t < 32; ++t){
      size_t r = (size_t)(rowS + t);
      float dtu = bits2f(DTBu[r * 128 + d]);
      float xcv = bits2f(XCBu[r * 128 + d]);
      float zv  = bits2f(XZu[r * 256 + 128 + d]);
      const uint4* bp = (const uint4*)(BCBu + r * 32);
      uint4 q0 = bp[0], q1 = bp[1], q2 = bp[2], q3 = bp[3];
      float Bv[16], Cv[16];
      up2(q0.x, Bv[0], Bv[1]);  up2(q0.y, Bv[2], Bv[3]);  up2(q0.z, Bv[4], Bv[5]);  up2(q0.w, Bv[6], Bv[7]);
      up2(q1.x, Bv[8], Bv[9]);  up2(q1.y, Bv[10], Bv[11]); up2(q1.z, Bv[12], Bv[13]); up2(q1.w, Bv[14], Bv[15]);
      up2(q2.x, Cv[0], Cv[1]);  up2(q2.y, Cv[2], Cv[3]);  up2(q2.z, Cv[4], Cv[5]);  up2(q2.w, Cv[6], Cv[7]);
      up2(q3.x, Cv[8], Cv[9]);  up2(q3.y, Cv[10], Cv[11]); up2(q3.z, Cv[12], Cv[13]); up2(q3.w, Cv[14], Cv[15]);
      float dx = dtu * xcv;
      float aa[16];
      if (apat){
        powchain(__expf(-dtu), aa);
      } else {
        #pragma unroll
        for (int s = 0; s < 16; ++s) aa[s] = __expf(dtu * A[s]);
      }
      float y = 0.f;
      #pragma unroll
      for (int s = 0; s < 16; ++s){
        h[s] = fmaf(aa[s], h[s], dx * Bv[s]);
        y = fmaf(h[s], Cv[s], y);
      }
      y = fmaf(Dv, xcv, y);
      u16 yv = f2bu(y * silu_f(zv));
      if (half == 0) yf_s[t][d] = yv;
      else           yb_s[31 - t][d] = yv;
    }
  }
  __syncthreads();

  int w = tid >> 6, lane = tid & 63;
  int l15 = lane & 15, ko = lane >> 4;
  int mt = w & 1, nh = w >> 1;
  const u16* wf = (const u16*)out_w + (size_t)df * 8192;
  const u16* wb = (const u16*)out_w + (size_t)db_ * 8192;
  short8v Af[4], Ab[4];
  #pragma unroll
  for (int kk = 0; kk < 4; ++kk){
    Af[kk] = *(const short8v*)&yf_s[mt * 16 + l15][kk * 32 + ko * 8];
    Ab[kk] = *(const short8v*)&yb_s[mt * 16 + l15][kk * 32 + ko * 8];
  }
  float* xo = ws + ((pair == 0) ? XS_OFF : (pair == 1) ? XTG_OFF : XTD_OFF);
  int Lout = (pair < 2) ? 4096 : 1024;
  u16* xsb = (u16*)(ws + XSB_OFF);
  #pragma unroll
  for (int ct = 0; ct < 2; ++ct){
    int c = nh * 32 + ct * 16 + l15;
    f32x4 acc = {0.f, 0.f, 0.f, 0.f};
    #pragma unroll
    for (int kk = 0; kk < 4; ++kk){
      short8v Bf = *(const short8v*)(wf + (size_t)c * 128 + kk * 32 + ko * 8);
      acc = __builtin_amdgcn_mfma_f32_16x16x32_bf16(Af[kk], Bf, acc, 0, 0, 0);
      short8v Bb = *(const short8v*)(wb + (size_t)c * 128 + kk * 32 + ko * 8);
      acc = __builtin_amdgcn_mfma_f32_16x16x32_bf16(Ab[kk], Bb, acc, 0, 0, 0);
    }
    #pragma unroll
    for (int reg = 0; reg < 4; ++reg){
      int row = l0 + mt * 16 + ko * 4 + reg;
      float v = 0.5f * acc[reg];
      xo[((size_t)b * Lout + row) * 64 + c] = v;
      if (pair == 0) xsb[((size_t)b * 4096 + row) * 64 + c] = f2bu(v);
    }
  }
}

// ---------------- k_convmfma (+per-block GN partial store; plain stores, no contention) ----------
template<int NTAP>
__global__ __launch_bounds__(256) void k_convmfma(const bf16* __restrict__ act,
        float* __restrict__ outf, bf16* __restrict__ outb,
        const bf16* __restrict__ wt, const bf16* __restrict__ bias,
        float* __restrict__ part){
  __shared__ float red[4][4];
  int wid = blockIdx.x * 4 + (threadIdx.x >> 6);
  int lane = threadIdx.x & 63;
  int nc = wid & 1;
  int pt = wid >> 1;
  int b = pt >> 8, py = (pt >> 2) & 63, x0 = (pt & 3) << 4;
  int l15 = lane & 15, ko = lane >> 4;
  f32x4 acc0 = {0.f, 0.f, 0.f, 0.f}, acc1 = {0.f, 0.f, 0.f, 0.f};
  const bf16* ab = act + ((size_t)b * 4096) * 64;
  #pragma unroll
  for (int tap = 0; tap < NTAP; ++tap){
    int dy = (NTAP == 9) ? (tap / 3 - 1) : 0;
    int dx = (NTAP == 9) ? (tap % 3 - 1) : 0;
    int y = py + dy;
    bool yok = (NTAP == 1) || ((unsigned)y < 64u);
    int xx = x0 + l15 + dx;
    bool vall = yok && ((NTAP == 1) || ((unsigned)xx < 64u));
    const bf16* arow = ab + ((size_t)(y * 64 + xx)) * 64;
    const bf16* wrow = wt + (size_t)tap * 4096;
    #pragma unroll
    for (int kk = 0; kk < 2; ++kk){
      int ci0 = kk * 32 + ko * 8;
      short8v a;
      if (vall) a = *(const short8v*)(arow + ci0); else a = zero8();
      short8v bw0 = *(const short8v*)(wrow + (size_t)(nc * 32 + l15) * 64 + ci0);
      short8v bw1 = *(const short8v*)(wrow + (size_t)(nc * 32 + 16 + l15) * 64 + ci0);
      acc0 = __builtin_amdgcn_mfma_f32_16x16x32_bf16(a, bw0, acc0, 0, 0, 0);
      acc1 = __builtin_amdgcn_mfma_f32_16x16x32_bf16(a, bw1, acc1, 0, 0, 0);
    }
  }
  float bs0 = b2f(bias[nc * 32 + l15]);
  float bs1 = b2f(bias[nc * 32 + 16 + l15]);
  float s1a = 0.f, s2a = 0.f, s1b = 0.f, s2b = 0.f;
  size_t obase = ((size_t)b * 4096 + py * 64 + x0 + (ko << 2)) * 64 + nc * 32;
  #pragma unroll
  for (int r = 0; r < 4; ++r){
    float v0 = acc0[r] + bs0, v1 = acc1[r] + bs1;
    s1a += v0; s2a += v0 * v0; s1b += v1; s2b += v1 * v1;
    if (outf){
      outf[obase + (size_t)r * 64 + l15] = v0;
      outf[obase + (size_t)r * 64 + 16 + l15] = v1;
    } else {
      outb[obase + (size_t)r * 64 + l15] = __float2bfloat16(v0);
      outb[obase + (size_t)r * 64 + 16 + l15] = __float2bfloat16(v1);
    }
  }
  #pragma unroll
  for (int off = 1; off < 64; off <<= 1){
    s1a += __shfl_xor(s1a, off, 64); s2a += __shfl_xor(s2a, off, 64);
    s1b += __shfl_xor(s1b, off, 64); s2b += __shfl_xor(s2b, off, 64);
  }
  int w = threadIdx.x >> 6;
  if (lane == 0){ red[w][0] = s1a; red[w][1] = s2a; red[w][2] = s1b; red[w][3] = s2b; }
  __syncthreads();
  if (part && threadIdx.x < 8){
    int g = threadIdx.x >> 1, sel = threadIdx.x & 1;
    int w0 = g >> 1;
    int col = ((g & 1) << 1) + sel;
    part[(size_t)blockIdx.x * 8 + threadIdx.x] = red[w0][col] + red[w0 + 2][col];
  }
}

// ---------------- k_gn_act: prologue-reduce partials, then elementwise GN(+res)+gelu -------------
__global__ __launch_bounds__(256) void k_gn_act(const float* __restrict__ in, const float* __restrict__ res,
        bf16* __restrict__ outb, const float* __restrict__ part,
        const bf16* __restrict__ gw, const bf16* __restrict__ gb, int add_res){
  __shared__ float st8[8];
  int tid = threadIdx.x;
  int t = blockIdx.x * 256 + tid;
  int b = blockIdx.x >> 8;
  {
    int j = tid & 31, f = tid >> 5;
    float v = 0.f;
    #pragma unroll
    for (int k = 0; k < 4; ++k)
      v += part[(size_t)(b * 128 + j * 4 + k) * 8 + f];
    #pragma unroll
    for (int off = 16; off; off >>= 1) v += __shfl_down(v, off, 32);
    if (j == 0) st8[f] = v;
  }
  __syncthreads();
  int cq = t & 15, px = (t >> 4) & 4095;
  int c0 = cq * 4, g = cq >> 2;
  float mean = st8[g * 2] * (1.f / 65536.f);
  float rs = rsqrtf(st8[g * 2 + 1] * (1.f / 65536.f) - mean * mean + 1e-5f);
  size_t idx = ((size_t)b * 4096 + px) * 64 + c0;
  float4 f4 = *(const float4*)(in + idx);
  float vv[4] = {f4.x, f4.y, f4.z, f4.w};
  float rr[4] = {0.f, 0.f, 0.f, 0.f};
  if (add_res){ float4 r4 = *(const float4*)(res + idx); rr[0]=r4.x; rr[1]=r4.y; rr[2]=r4.z; rr[3]=r4.w; }
  u16 o[4];
  #pragma unroll
  for (int j = 0; j < 4; ++j){
    float v = (vv[j] - mean) * rs * b2f(gw[c0 + j]) + b2f(gb[c0 + j]);
    v += rr[j];
    o[j] = f2bu(gelu_f(v));
  }
  u32 lo = (u32)o[0] | ((u32)o[1] << 16);
  u32 hi = (u32)o[2] | ((u32)o[3] << 16);
  *(uint2*)((u16*)outb + idx) = make_uint2(lo, hi);
}

// ---------------- k_dwgelu ----------------
__global__ __launch_bounds__(256) void k_dwgelu(const bf16* __restrict__ in, bf16* __restrict__ out,
        const bf16* __restrict__ w, const bf16* __restrict__ bias){
  int id = blockIdx.x * 256 + threadIdx.x;
  int oc8 = id & 7, px = (id >> 3) & 4095, b = id >> 15;
  int py = px >> 6, pxx = px & 63;
  float wv[8][9];
  #pragma unroll
  for (int j = 0; j < 8; ++j)
    #pragma unroll
    for (int tp = 0; tp < 9; ++tp) wv[j][tp] = b2f(w[(oc8 * 8 + j) * 9 + tp]);
  float acc[8];
  #pragma unroll
  for (int j = 0; j < 8; ++j) acc[j] = b2f(bias[oc8 * 8 + j]);
  const bf16* inb = in + ((size_t)b * 4096) * 64;
  #pragma unroll
  for (int dy = 0; dy < 3; ++dy){
    int y = py + dy - 1;
    if ((unsigned)y >= 64u) continue;
    #pragma unroll
    for (int dx = 0; dx < 3; ++dx){
      int x = pxx + dx - 1;
      if ((unsigned)x >= 64u) continue;
      short8v iv = *(const short8v*)(inb + ((size_t)(y * 64 + x)) * 64 + oc8 * 8);
      #pragma unroll
      for (int j = 0; j < 8; ++j)
        acc[j] = fmaf(bits2f((u16)iv[j]), wv[j][dy * 3 + dx], acc[j]);
    }
  }
  u32 pk[4];
  #pragma unroll
  for (int k = 0; k < 4; ++k){
    u16 a0 = f2bu(gelu_f(acc[2 * k]));
    u16 a1 = f2bu(gelu_f(acc[2 * k + 1]));
    pk[k] = (u32)a0 | ((u32)a1 << 16);
  }
  *(uint4*)((u16*)out + ((size_t)b * 4096 + px) * 64 + oc8 * 8) = make_uint4(pk[0], pk[1], pk[2], pk[3]);
}

// ---------------- k_final: prologue-reduce partials, then fuse + upsample + sum -------------------
__global__ __launch_bounds__(256) void k_final(const float* __restrict__ ws, void* __restrict__ outp,
        const bf16* __restrict__ gw, const bf16* __restrict__ gb){
  __shared__ float st8[8];
  int flag = *(const int*)(ws + FLAG_OFF);
  int bid = blockIdx.x;
  int b = bid >> 6, py = bid & 63;
  int t = threadIdx.x;
  {
    const float* part = ws + PART_OFF + 3 * 2048;
    int j = t & 31, f = t >> 5;
    float v = 0.f;
    #pragma unroll
    for (int k = 0; k < 4; ++k)
      v += part[(size_t)(b * 128 + j * 4 + k) * 8 + f];
    #pragma unroll
    for (int off = 16; off; off >>= 1) v += __shfl_down(v, off, 32);
    if (j == 0) st8[f] = v;
  }
  __syncthreads();
  int c = t & 63, pxg = t >> 6;
  int g = c >> 4;
  float mean = st8[g * 2] * (1.f / 65536.f);
  float rs = rsqrtf(st8[g * 2 + 1] * (1.f / 65536.f) - mean * mean + 1e-5f);
  float gwv = b2f(gw[c]), gbv = b2f(gb[c]);
  const float* CV1 = ws + CV1_OFF;
  const bf16* PWB = (const bf16*)(ws + PWB_OFF);
  const float* XS = ws + XS_OFF;
  const float* XTG = ws + XTG_OFF;
  const float* XTD = ws + XTD_OFF + ((size_t)b * 1024) * 64;
  float sy = 0.5f * py - 0.25f;
  float fly = floorf(sy); float fy = sy - fly;
  int iy0 = max((int)fly, 0), iy1 = min((int)fly + 1, 31);
  float of[16];
  #pragma unroll
  for (int i = 0; i < 16; ++i){
    int px = pxg * 16 + i;
    size_t idx = ((size_t)b * 4096 + py * 64 + px) * 64 + c;
    float gn = (CV1[idx] - mean) * rs * gwv + gbv;
    float xl = gelu_f(b2f(PWB[idx]) + gn);
    float sx = 0.5f * px - 0.25f;
    float flx = floorf(sx); float fx = sx - flx;
    int ix0 = max((int)flx, 0), ix1 = min((int)flx + 1, 31);
    float v00 = XTD[(size_t)(iy0 * 32 + ix0) * 64 + c], v01 = XTD[(size_t)(iy0 * 32 + ix1) * 64 + c];
    float v10 = XTD[(size_t)(iy1 * 32 + ix0) * 64 + c], v11 = XTD[(size_t)(iy1 * 32 + ix1) * 64 + c];
    float tdv = (1.f - fy) * ((1.f - fx) * v00 + fx * v01) + fy * ((1.f - fx) * v10 + fx * v11);
    of[i] = XS[idx] + xl + 0.5f * XTG[idx] + 0.5f * tdv;
  }
  size_t ob = ((size_t)(b * 64 + c)) * 4096 + py * 64 + pxg * 16;
  if (flag){
    float* o = (float*)outp + ob;
    #pragma unroll
    for (int k = 0; k < 4; ++k)
      *(float4*)(o + k * 4) = make_float4(of[k*4], of[k*4+1], of[k*4+2], of[k*4+3]);
  } else {
    u16* o = (u16*)outp + ob;
    u32 pk[8];
    #pragma unroll
    for (int k = 0; k < 8; ++k)
      pk[k] = (u32)f2bu(of[2*k]) | ((u32)f2bu(of[2*k+1]) << 16);
    *(uint4*)(o) = make_uint4(pk[0], pk[1], pk[2], pk[3]);
    *(uint4*)(o + 8) = make_uint4(pk[4], pk[5], pk[6], pk[7]);
  }
}

// ---------------- launch ----------------
extern "C" void kernel_launch(void* const* d_in, const int* in_sizes, int n_in,
                              void* d_out, int out_size, void* d_ws, size_t ws_size,
                              hipStream_t stream) {
  float* ws = (float*)d_ws;
  bf16* prm = (bf16*)(ws + PRM_OFF);
  bf16* WT4 = (bf16*)(ws + WT4_OFF);
  bf16* XSB = (bf16*)(ws + XSB_OFF);
  bf16* A1B = (bf16*)(ws + A1B_OFF);
  bf16* A2B = (bf16*)(ws + A2B_OFF);
  bf16* PWBb = (bf16*)(ws + PWB_OFF);
  float* CV0 = ws + CV0_OFF;
  float* CV1 = ws + CV1_OFF;
  float* PART = ws + PART_OFF;

  const bf16* m_in_w   = prm + 0;
  const bf16* m_conv_w = prm + 98304;
  const bf16* m_conv_b = prm + 101376;
  const bf16* m_xproj  = prm + 102144;
  const bf16* m_dt_w   = prm + 129792;
  const bf16* m_dt_b   = prm + 132864;
  const bf16* m_A_log  = prm + 133632;
  const bf16* m_D      = prm + 145920;
  const bf16* m_out_w  = prm + 146688;
  const bf16* dw_w  = prm + 195840;
  const bf16* dw_b  = prm + 196416;
  const bf16* pw_w  = prm + 196480;
  const bf16* pw_b  = prm + 200576;
  const bf16* r1c1b = prm + 237504;
  const bf16* r1g1w = prm + 237568;
  const bf16* r1g1b = prm + 237632;
  const bf16* r1c2b = prm + 274560;
  const bf16* r1g2w = prm + 274624;
  const bf16* r1g2b = prm + 274688;
  const bf16* r2c1b = prm + 311616;
  const bf16* r2g1w = prm + 311680;
  const bf16* r2g1b = prm + 311744;
  const bf16* r2c2b = prm + 348672;
  const bf16* r2g2w = prm + 348736;
  const bf16* r2g2b = prm + 348800;

  P29 ptrs;
  for (int t = 0; t < 29; ++t) ptrs.p[t] = d_in[t + 1];

  k_detect<<<1, 256, 0, stream>>>(d_in[0], d_in[7], ws);
  k_setup<<<4499, 256, 0, stream>>>(ptrs, d_in[0], ws);
  k_front<<<1152, 256, 0, stream>>>(ws, m_in_w, m_xproj, m_dt_w, m_dt_b, m_conv_w, m_conv_b, m_A_log);
  k_scan2<<<96, 256, 0, stream>>>(ws);
  k_outproj<<<576, 256, 0, stream>>>(ws, m_out_w, m_A_log, m_D);

  // conv branch (NHWC); GN partials from conv epilogue, reduced in consumers
  k_convmfma<9><<<256, 256, 0, stream>>>(XSB, CV0, (bf16*)nullptr, WT4 + 0 * 36864, r1c1b, PART + 0 * 2048);
  k_gn_act<<<512, 256, 0, stream>>>(CV0, (const float*)nullptr, A1B, PART + 0 * 2048, r1g1w, r1g1b, 0);
  k_convmfma<9><<<256, 256, 0, stream>>>(A1B, CV1, (bf16*)nullptr, WT4 + 1 * 36864, r1c2b, PART + 1 * 2048);
  k_gn_act<<<512, 256, 0, stream>>>(CV1, ws + XS_OFF, A2B, PART + 1 * 2048, r1g2w, r1g2b, 1);
  k_dwgelu<<<256, 256, 0, stream>>>(A2B, A1B, dw_w, dw_b);
  k_convmfma<1><<<256, 256, 0, stream>>>(A1B, (float*)nullptr, PWBb, pw_w, pw_b, (float*)nullptr);
  k_convmfma<9><<<256, 256, 0, stream>>>(PWBb, CV0, (bf16*)nullptr, WT4 + 2 * 36864, r2c1b, PART + 2 * 2048);
  k_gn_act<<<512, 256, 0, stream>>>(CV0, (const float*)nullptr, A1B, PART + 2 * 2048, r2g1w, r2g1b, 0);
  k_convmfma<9><<<256, 256, 0, stream>>>(A1B, CV1, (bf16*)nullptr, WT4 + 3 * 36864, r2c2b, PART + 3 * 2048);
  k_final<<<128, 256, 0, stream>>>(ws, d_out, r2g2w, r2g2b);
}

// Round 16
// 206.802 us; speedup vs baseline: 1.0069x; 1.0069x over previous
//
#include <hip/hip_runtime.h>
#include <hip/hip_bf16.h>

typedef __hip_bfloat16 bf16;
typedef unsigned short u16;
typedef unsigned int u32;
typedef __attribute__((ext_vector_type(8))) short short8v;
typedef __attribute__((ext_vector_type(4))) float f32x4;

// ---------------- geometry ----------------
// 12 scan problems: g = dir*2+b for dir 0..3 (L=4096), g = 8.. (L=1024)
// T_TOT rows = 36864. Chunk Lc=32 -> 1152 chunks. k_front: 1152 blocks x 1 chunk x 2 t-halves.
// k_outproj: fused scan3 + GEMM. GN stats: per-block partials from conv epilogue (plain stores,
// 256 disjoint addresses — NEVER hot atomics), reduced in gn_act/final prologue.

// ---------------- workspace layout (float units) ----------------
#define XCB_OFF   0u            /* bf16 [36864][128] conv-x */
#define DTB_OFF   2359296u      /* bf16 [36864][128] dt */
#define BCB_OFF   4718592u      /* bf16 [36864][32]  B(16) C(16) */
#define CHA_OFF   5308416u      /* f32 [1152][2048] chunk a-products */
#define CHH_OFF   7667712u      /* f32 [1152][2048] chunk h / carry-in */
#define XZ_OFF    10027008u     /* bf16 [36864][256] in_proj out (x | z) */
#define UFS_OFF   14745600u     /* f32 (B,L,64) full-res */
#define UFD_OFF   15269888u     /* f32 (B,1024,64) downsampled */
#define XS_OFF    15400960u     /* f32 NHWC [2][4096][64] */
#define XTG_OFF   15925248u
#define XTD_OFF   16449536u     /* f32 NHWC [2][1024][64] */
#define XSB_OFF   16580608u     /* bf16 NHWC copy of XS */
#define WT4_OFF   16842752u     /* bf16 [4][9][64][64] conv weights frag order */
#define STATS_OFF 16916480u     /* legacy, unused */
#define FLAG_OFF  16916736u     /* [0] dtype flag, [1] A-pattern flag */
#define PRM_OFF   16916752u     /* bf16 staging, 348864 entries */
#define PART_OFF  17091184u     /* f32 [4 stages][256 blocks][8] GN partials */
/* conv-branch aliases in dead XCB/DTB region (after k_outproj) */
#define CV0_OFF   0u
#define CV1_OFF   524288u
#define A1B_OFF   1048576u
#define A2B_OFF   1310720u
#define PWB_OFF   1572864u

__device__ __forceinline__ float bits2f(u16 v){
  u32 u = ((u32)v) << 16; float f; __builtin_memcpy(&f, &u, 4); return f;
}
__device__ __forceinline__ float b2f(bf16 v){ return __bfloat162float(v); }
__device__ __forceinline__ u16 f2bu(float f){ bf16 h = __float2bfloat16(f); u16 b; __builtin_memcpy(&b, &h, 2); return b; }
__device__ __forceinline__ float silu_f(float x){ return x / (1.f + __expf(-x)); }
__device__ __forceinline__ float softplus_f(float x){ return fmaxf(x, 0.f) + log1pf(__expf(-fabsf(x))); }
__device__ __forceinline__ float gelu_f(float x){ return 0.5f * x * (1.f + erff(x * 0.70710678118654752f)); }
__device__ __forceinline__ short8v zero8(){ short8v z = {0,0,0,0,0,0,0,0}; return z; }
__device__ __forceinline__ void up2(u32 w, float& a, float& b){
  a = bits2f((u16)(w & 0xffffu)); b = bits2f((u16)(w >> 16));
}
// aa[s] = r^(s+1), depth-4 multiply tree
__device__ __forceinline__ void powchain(float r, float* aa){
  aa[0]=r; aa[1]=r*r; aa[2]=aa[1]*r; aa[3]=aa[1]*aa[1];
  aa[4]=aa[3]*r; aa[5]=aa[3]*aa[1]; aa[6]=aa[3]*aa[2]; aa[7]=aa[3]*aa[3];
  aa[8]=aa[7]*r; aa[9]=aa[7]*aa[1]; aa[10]=aa[7]*aa[2]; aa[11]=aa[7]*aa[3];
  aa[12]=aa[7]*aa[4]; aa[13]=aa[7]*aa[5]; aa[14]=aa[7]*aa[6]; aa[15]=aa[7]*aa[7];
}

struct P29 { const void* p[29]; };

__constant__ int PREF[30] = {0, 98304, 101376, 102144, 129792, 132864, 133632,
  145920, 146688, 195840, 196416, 196480, 200576, 200640, 237504, 237568,
  237632, 237696, 274560, 274624, 274688, 274752, 311616, 311680, 311744,
  311808, 348672, 348736, 348800, 348864};

__constant__ float LOGT[16] = {0.0f, 0.6931472f, 1.0986123f, 1.3862944f,
  1.6094379f, 1.7917595f, 1.9459101f, 2.0794415f, 2.1972246f, 2.3025851f,
  2.3978953f, 2.4849067f, 2.5649493f, 2.6390573f, 2.7080502f, 2.7725887f};

// ---------------- k_detect: dtype flag + A_log pattern flag ----------------
__global__ void k_detect(const void* __restrict__ xraw, const void* __restrict__ araw,
                         float* __restrict__ ws){
  __shared__ int cnt_s, bad_s;
  int tid = threadIdx.x;
  if (tid == 0){ cnt_s = 0; bad_s = 0; }
  __syncthreads();
  const u16* p = (const u16*)xraw;
  int c = 0;
  for (int i = tid; i < 4096; i += 256){
    int e = (p[i] >> 7) & 0xFF;
    if (e >= 0x77 && e <= 0x87) c++;
  }
  atomicAdd(&cnt_s, c);
  __syncthreads();
  int flag = (cnt_s > 3500) ? 0 : 1;   // 1 -> f32 inputs, 0 -> bf16 inputs
  int bad = 0;
  for (int i = tid; i < 12288; i += 256){
    float v = flag ? ((const float*)araw)[i] : b2f(((const bf16*)araw)[i]);
    if (fabsf(v - LOGT[i & 15]) > 0.02f) bad = 1;
  }
  if (bad) atomicAdd(&bad_s, 1);
  __syncthreads();
  if (tid == 0){
    ((int*)(ws + FLAG_OFF))[0] = flag;
    ((int*)(ws + FLAG_OFF))[1] = (bad_s == 0) ? 1 : 0;
  }
}

// ---------------- k_setup: fused cvt + prep + wprep ----------------
__global__ __launch_bounds__(256) void k_setup(P29 ptrs, const void* __restrict__ xraw,
                                               float* __restrict__ ws){
  int bid = blockIdx.x, tid = threadIdx.x;
  int flag = *(const int*)(ws + FLAG_OFF);
  const float* xf = (const float*)xraw;
  const bf16*  xb = (const bf16*)xraw;
  if (bid < 2560){
    int i = bid * 256 + tid;
    if (i < 524288){
      int b = i >> 18, rem = i & 262143, l = rem >> 6, d = rem & 63;
      size_t idx = (size_t)b*262144 + d*4096 + l;
      ws[UFS_OFF + i] = flag ? xf[idx] : b2f(xb[idx]);
    } else if (i < 655360){
      int j = i - 524288;
      int b = j >> 16, rem = j & 65535, l = rem >> 6, d = rem & 63;
      int i2 = l >> 5, j2 = l & 31;
      size_t base = (size_t)b*262144 + d*4096 + (i2*2)*64 + j2*2;
      float v0, v1, v2, v3;
      if (flag){ v0 = xf[base]; v1 = xf[base+1]; v2 = xf[base+64]; v3 = xf[base+65]; }
      else     { v0 = b2f(xb[base]); v1 = b2f(xb[base+1]); v2 = b2f(xb[base+64]); v3 = b2f(xb[base+65]); }
      ws[UFD_OFF + j] = 0.25f * (v0 + v1 + v2 + v3);
    }
  } else if (bid < 3923){
    int i = (bid - 2560) * 256 + tid;
    if (i < 348864){
      int t = 0;
      #pragma unroll 1
      while (i >= PREF[t + 1]) ++t;
      int off = i - PREF[t];
      float v = flag ? ((const float*)ptrs.p[t])[off]
                     : b2f(((const bf16*)ptrs.p[t])[off]);
      ((bf16*)(ws + PRM_OFF))[i] = __float2bfloat16(v);
    }
  } else {
    int i = (bid - 3923) * 256 + tid;
    if (i < 147456){
      int conv = i / 36864, r = i - conv * 36864;
      int tap = r >> 12, co = (r >> 6) & 63, ci = r & 63;
      const int SRC[4] = {13, 17, 21, 25};
      const void* sp_ = ptrs.p[SRC[conv]];
      size_t off = (size_t)co * 576 + ci * 9 + tap;
      float v = flag ? ((const float*)sp_)[off] : b2f(((const bf16*)sp_)[off]);
      ((bf16*)(ws + WT4_OFF))[i] = __float2bfloat16(v);
    }
  }
}

__device__ __forceinline__ void chunk_map(int bid, int& g, int& c0){
  if (bid < 1024){ g = bid >> 7; c0 = bid & 127; }
  else { int r = bid - 1024; g = 8 + (r >> 5); c0 = r & 31; }
}

// ---------------- k_inproj (MFMA, 32-row tiles): XZ[32][256] = U_bf16 @ in_w^T -------------------
__global__ __launch_bounds__(256) void k_inproj(const float* __restrict__ ws,
        bf16* __restrict__ XZ, const bf16* __restrict__ in_w){
  __shared__ __align__(16) u16 u_s[32][72];
  int g, tile; chunk_map(blockIdx.x, g, tile);
  int dir = (g < 8) ? (g >> 1) : 4 + ((g - 8) >> 1);
  int b   = (g < 8) ? (g & 1) : ((g - 8) & 1);
  int rev = dir & 1;
  int L   = (g < 8) ? 4096 : 1024;
  int row0 = (g < 8) ? g * 4096 : 32768 + (g - 8) * 1024;
  int t0 = tile * 32;
  const float* U = (g < 8) ? (ws + UFS_OFF + (size_t)b * 262144)
                           : (ws + UFD_OFF + (size_t)b * 65536);
  int tid = threadIdx.x;
  for (int e = tid; e < 2048; e += 256){
    int i = e >> 6, d = e & 63;
    int l = rev ? (L - 1 - (t0 + i)) : (t0 + i);
    u_s[i][d] = f2bu(U[(size_t)l * 64 + d]);
  }
  __syncthreads();
  int w = tid >> 6, lane = tid & 63;
  int l15 = lane & 15, ko = lane >> 4;
  short8v Au[2][2];
  #pragma unroll
  for (int mt = 0; mt < 2; ++mt)
    #pragma unroll
    for (int kk = 0; kk < 2; ++kk)
      Au[mt][kk] = *(const short8v*)&u_s[mt * 16 + l15][kk * 32 + ko * 8];
  const u16* wg = (const u16*)in_w + (size_t)dir * 16384;
  u16* XZu = (u16*)XZ;
  #pragma unroll
  for (int nq = 0; nq < 4; ++nq){
    int nt = w * 4 + nq;
    int c = nt * 16 + l15;
    short8v B0 = *(const short8v*)(wg + (size_t)c * 64 + ko * 8);
    short8v B1 = *(const short8v*)(wg + (size_t)c * 64 + 32 + ko * 8);
    #pragma unroll
    for (int mt = 0; mt < 2; ++mt){
      f32x4 acc = {0.f, 0.f, 0.f, 0.f};
      acc = __builtin_amdgcn_mfma_f32_16x16x32_bf16(Au[mt][0], B0, acc, 0, 0, 0);
      acc = __builtin_amdgcn_mfma_f32_16x16x32_bf16(Au[mt][1], B1, acc, 0, 0, 0);
      #pragma unroll
      for (int reg = 0; reg < 4; ++reg){
        int t = t0 + mt * 16 + ko * 4 + reg;
        XZu[(size_t)(row0 + t) * 256 + c] = f2bu(acc[reg]);
      }
    }
  }
}

// ---------------- k_front: conv+silu + x_proj(MFMA) + dt + half-split chunk scan -----------------
__global__ __launch_bounds__(256) void k_front(float* __restrict__ ws,
        const bf16* __restrict__ xproj_w, const bf16* __restrict__ dt_w, const bf16* __restrict__ dt_b,
        const bf16* __restrict__ conv_w, const bf16* __restrict__ conv_b, const bf16* __restrict__ A_log){
  __shared__ __align__(16) u32 xstage[2310];    // halo [35][66] u32; later xp_s f32 [32][40]
  __shared__ __align__(16) u16 xc_s[32][136];
  __shared__ __align__(16) u32 blob[4352];      // xw_s u16[48][136] (3264 u32) / cmb f32[4352]
  float* xp_s = (float*)xstage;
  u16* xw_s = (u16*)blob;
  float* cmb = (float*)blob;                    // P0 at [c*17+s], H0 at [2176 + c*17+s]

  int g, c0; chunk_map(blockIdx.x, g, c0);
  int dir = (g < 8) ? (g >> 1) : 4 + ((g - 8) >> 1);
  int grow0 = (g < 8) ? g * 4096 : 32768 + (g - 8) * 1024;
  int t0 = c0 << 5;
  int crow = ((g < 8) ? g * 128 : 1024 + (g - 8) * 32) + c0;
  int tid = threadIdx.x;

  const u32* XZ32 = (const u32*)(ws + XZ_OFF);
  for (int e = tid; e < 2240; e += 256){
    int lr = e >> 6, col = e & 63;
    int gt = t0 - 3 + lr;
    u32 v = 0u;
    if (gt >= 0) v = XZ32[(size_t)(grow0 + gt) * 128 + col];
    xstage[lr * 66 + col] = v;
  }
  const u16* xw = (const u16*)xproj_w + (size_t)dir * 4608;
  for (int e = tid; e < 6144; e += 256){
    int m = e >> 7, col = e & 127;
    xw_s[m * 136 + col] = (m < 36) ? xw[m * 128 + col] : (u16)0;
  }
  __syncthreads();

  int c = tid & 127, hf = tid >> 7;
  int rb = hf * 16;
  // phase 1: causal conv + silu
  {
    const u16* cwp = (const u16*)conv_w + (size_t)dir * 512 + c * 4;
    uint2 cw2 = *(const uint2*)cwp;
    float cw0, cw1, cw2f, cw3;
    up2(cw2.x, cw0, cw1); up2(cw2.y, cw2f, cw3);
    float cb = b2f(conv_b[dir * 128 + c]);
    const u16* xsu = (const u16*)xstage;
    float xm3 = bits2f(xsu[rb * 132 + c]);
    float xm2 = bits2f(xsu[(rb + 1) * 132 + c]);
    float xm1 = bits2f(xsu[(rb + 2) * 132 + c]);
    u16* XCBu = (u16*)(ws + XCB_OFF);
    #pragma unroll 4
    for (int t = 0; t < 16; ++t){
      float xcur = bits2f(xsu[(rb + t + 3) * 132 + c]);
      float s = cb + cw0 * xm3 + cw1 * xm2 + cw2f * xm1 + cw3 * xcur;
      u16 xbv = f2bu(silu_f(s));
      xm3 = xm2; xm2 = xm1; xm1 = xcur;
      xc_s[rb + t][c] = xbv;
      XCBu[(size_t)(grow0 + t0 + rb + t) * 128 + c] = xbv;
    }
  }
  __syncthreads();

  // phase 2: x_proj via MFMA
  {
    int w = tid >> 6, lane = tid & 63;
    int l15 = lane & 15, ko = lane >> 4;
    for (int task = w; task < 6; task += 4){
      int mt = task & 1, nt = task >> 1;
      f32x4 acc = {0.f, 0.f, 0.f, 0.f};
      #pragma unroll
      for (int kk = 0; kk < 4; ++kk){
        short8v Afr = *(const short8v*)&xc_s[mt * 16 + l15][kk * 32 + ko * 8];
        short8v Bfr = *(const short8v*)(xw_s + (size_t)(nt * 16 + l15) * 136 + kk * 32 + ko * 8);
        acc = __builtin_amdgcn_mfma_f32_16x16x32_bf16(Afr, Bfr, acc, 0, 0, 0);
      }
      int j = nt * 16 + l15;
      if (j < 36){
        #pragma unroll
        for (int reg = 0; reg < 4; ++reg){
          int t = mt * 16 + ko * 4 + reg;
          xp_s[t * 40 + j] = acc[reg];
        }
      }
    }
  }
  __syncthreads();

  // phase 2.5: round B/C to bf16 + write BCB
  {
    u16* BCBu = (u16*)(ws + BCB_OFF);
    for (int e = tid; e < 1024; e += 256){
      int t = e >> 5, v = e & 31;
      float val = xp_s[t * 40 + 4 + v];
      u16 r = f2bu(val);
      xp_s[t * 40 + 4 + v] = bits2f(r);
      BCBu[(size_t)(grow0 + t0 + t) * 32 + v] = r;
    }
  }
  __syncthreads();

  // phase 3: dt + 16-step local scan per half + combine
  {
    int apat = ((const int*)(ws + FLAG_OFF))[1];
    float A[16];
    const u16* ap = (const u16*)A_log + (size_t)dir * 2048 + c * 16;
    #pragma unroll
    for (int s = 0; s < 16; ++s) A[s] = -__expf(bits2f(ap[s]));
    const u16* dwp = (const u16*)dt_w + (size_t)dir * 512 + c * 4;
    uint2 dw2 = *(const uint2*)dwp;
    float d0, d1, d2, d3;
    up2(dw2.x, d0, d1); up2(dw2.y, d2, d3);
    float db = b2f(dt_b[dir * 128 + c]);
    u16* DTBu = (u16*)(ws + DTB_OFF);
    float hh[16], p[16];
    #pragma unroll
    for (int s = 0; s < 16; ++s){ hh[s] = 0.f; p[s] = 1.f; }
    float dtsum = 0.f;
    #pragma unroll 2
    for (int t = 0; t < 16; ++t){
      float4 xp4 = *(const float4*)&xp_s[(rb + t) * 40];
      float dtv = softplus_f(db + d0 * xp4.x + d1 * xp4.y + d2 * xp4.z + d3 * xp4.w);
      u16 dtb16 = f2bu(dtv);
      DTBu[(size_t)(grow0 + t0 + rb + t) * 128 + c] = dtb16;
      float dtu = bits2f(dtb16);
      float xcv = bits2f(xc_s[rb + t][c]);
      float dx = dtu * xcv;
      float aa[16];
      if (apat){
        dtsum += dtu;
        powchain(__expf(-dtu), aa);
      } else {
        #pragma unroll
        for (int s = 0; s < 16; ++s) aa[s] = __expf(dtu * A[s]);
        #pragma unroll
        for (int s = 0; s < 16; ++s) p[s] *= aa[s];
      }
      #pragma unroll
      for (int s = 0; s < 16; ++s)
        hh[s] = fmaf(aa[s], hh[s], dx * xp_s[(rb + t) * 40 + 4 + s]);
    }
    if (apat) powchain(__expf(-dtsum), p);
    if (hf == 0){
      #pragma unroll
      for (int s = 0; s < 16; ++s){
        cmb[c * 17 + s] = p[s];
        cmb[2176 + c * 17 + s] = hh[s];
      }
    }
    __syncthreads();
    if (hf == 1){
      float ca[16], ch[16];
      #pragma unroll
      for (int s = 0; s < 16; ++s){
        float P0 = cmb[c * 17 + s];
        float H0 = cmb[2176 + c * 17 + s];
        ca[s] = P0 * p[s];
        ch[s] = fmaf(p[s], H0, hh[s]);
      }
      float* CA = ws + CHA_OFF + (size_t)crow * 2048 + c * 16;
      float* CH = ws + CHH_OFF + (size_t)crow * 2048 + c * 16;
      #pragma unroll
      for (int q = 0; q < 4; ++q){
        *(float4*)(CA + q * 4) = make_float4(ca[q*4], ca[q*4+1], ca[q*4+2], ca[q*4+3]);
        *(float4*)(CH + q * 4) = make_float4(ch[q*4], ch[q*4+1], ch[q*4+2], ch[q*4+3]);
      }
    }
  }
}

// ---------------- k_scan2: sequential carry across chunks (unrolled x8) ----------------
__global__ __launch_bounds__(256) void k_scan2(float* __restrict__ ws){
  int id = blockIdx.x * 256 + threadIdx.x;
  int gi = id >> 11, dsl = id & 2047;
  int nc = (gi < 8) ? 128 : 32;
  int cb = (gi < 8) ? gi * 128 : 1024 + (gi - 8) * 32;
  float* CA = ws + CHA_OFF; float* CH = ws + CHH_OFF;
  float hprev = 0.f;
  for (int ch = 0; ch < nc; ch += 8){
    size_t i0 = (size_t)(cb + ch) * 2048 + dsl;
    float a[8], hv[8];
    #pragma unroll
    for (int j = 0; j < 8; ++j){
      a[j] = CA[i0 + (size_t)j * 2048];
      hv[j] = CH[i0 + (size_t)j * 2048];
    }
    #pragma unroll
    for (int j = 0; j < 8; ++j){
      CH[i0 + (size_t)j * 2048] = hprev;
      hprev = fmaf(a[j], hprev, hv[j]);
    }
  }
}

// ---------------- k_outproj: FUSED scan3 + MFMA GEMM ------------------------------------------
__global__ __launch_bounds__(256) void k_outproj(float* __restrict__ ws, const bf16* __restrict__ out_w,
        const bf16* __restrict__ A_log, const bf16* __restrict__ Dp){
  __shared__ __align__(16) u16 yf_s[32][132];
  __shared__ __align__(16) u16 yb_s[32][132];
  int bid = blockIdx.x;
  int pair, b, tile, L;
  if (bid < 512){ pair = bid >> 8; b = (bid >> 7) & 1; tile = bid & 127; L = 4096; }
  else { int r = bid - 512; pair = 2; b = r >> 5; tile = r & 31; L = 1024; }
  int l0 = tile * 32;
  int ncht = L >> 5;
  int df = pair * 2, db_ = df + 1;
  int gf = (pair < 2) ? df * 2 + b : 8 + b;
  int gb = (pair < 2) ? db_ * 2 + b : 10 + b;
  int rowf0 = (gf < 8) ? gf * 4096 : 32768 + (gf - 8) * 1024;
  int rowb0 = (gb < 8) ? gb * 4096 : 32768 + (gb - 8) * 1024;
  int tid = threadIdx.x;

  {
    int half = tid >> 7, d = tid & 127;
    int gS = half ? gb : gf;
    int dirS = (gS < 8) ? (gS >> 1) : 4 + ((gS - 8) >> 1);
    int rowS = half ? (rowb0 + (L - 32 - l0)) : (rowf0 + l0);
    int cbaseS = (gS < 8) ? gS * 128 : 1024 + (gS - 8) * 32;
    int crowS = cbaseS + (half ? (ncht - 1 - tile) : tile);
    int apat = ((const int*)(ws + FLAG_OFF))[1];
    float A[16];
    const u16* ap = (const u16*)A_log + (size_t)dirS * 2048 + d * 16;
    #pragma unroll
    for (int s = 0; s < 16; ++s) A[s] = -__expf(bits2f(ap[s]));
    float h[16];
    const float* CH = ws + CHH_OFF + (size_t)crowS * 2048 + d * 16;
    #pragma unroll
    for (int s = 0; s < 16; ++s) h[s] = CH[s];
    float Dv = b2f(Dp[dirS * 128 + d]);
    const u16* XCBu = (const u16*)(ws + XCB_OFF);
    const u16* DTBu = (const u16*)(ws + DTB_OFF);
    const u16* BCBu = (const u16*)(ws + BCB_OFF);
    const u16* XZu  = (const u16*)(ws + XZ_OFF);
    #pragma unroll 2
    for (int t = 0; t < 32; ++t){
      size_t r = (size_t)(rowS + t);
      float dtu = bits2f(DTBu[r * 128 + d]);
      float xcv = bits2f(XCBu[r * 128 + d]);
      float zv  = bits2f(XZu[r * 256 + 128 + d]);
      const uint4* bp = (const uint4*)(BCBu + r * 32);
      uint4 q0 = bp[0], q1 = bp[1], q2 = bp[2], q3 = bp[3];
      float Bv[16], Cv[16];
      up2(q0.x, Bv[0], Bv[1]);  up2(q0.y, Bv[2], Bv[3]);  up2(q0.z, Bv[4], Bv[5]);  up2(q0.w, Bv[6], Bv[7]);
      up2(q1.x, Bv[8], Bv[9]);  up2(q1.y, Bv[10], Bv[11]); up2(q1.z, Bv[12], Bv[13]); up2(q1.w, Bv[14], Bv[15]);
      up2(q2.x, Cv[0], Cv[1]);  up2(q2.y, Cv[2], Cv[3]);  up2(q2.z, Cv[4], Cv[5]);  up2(q2.w, Cv[6], Cv[7]);
      up2(q3.x, Cv[8], Cv[9]);  up2(q3.y, Cv[10], Cv[11]); up2(q3.z, Cv[12], Cv[13]); up2(q3.w, Cv[14], Cv[15]);
      float dx = dtu * xcv;
      float aa[16];
      if (apat){
        powchain(__expf(-dtu), aa);
      } else {
        #pragma unroll
        for (int s = 0; s < 16; ++s) aa[s] = __expf(dtu * A[s]);
      }
      float y = 0.f;
      #pragma unroll
      for (int s = 0; s < 16; ++s){
        h[s] = fmaf(aa[s], h[s], dx * Bv[s]);
        y = fmaf(h[s], Cv[s], y);
      }
      y = fmaf(Dv, xcv, y);
      u16 yv = f2bu(y * silu_f(zv));
      if (half == 0) yf_s[t][d] = yv;
      else           yb_s[31 - t][d] = yv;
    }
  }
  __syncthreads();

  int w = tid >> 6, lane = tid & 63;
  int l15 = lane & 15, ko = lane >> 4;
  int mt = w & 1, nh = w >> 1;
  const u16* wf = (const u16*)out_w + (size_t)df * 8192;
  const u16* wb = (const u16*)out_w + (size_t)db_ * 8192;
  short8v Af[4], Ab[4];
  #pragma unroll
  for (int kk = 0; kk < 4; ++kk){
    Af[kk] = *(const short8v*)&yf_s[mt * 16 + l15][kk * 32 + ko * 8];
    Ab[kk] = *(const short8v*)&yb_s[mt * 16 + l15][kk * 32 + ko * 8];
  }
  float* xo = ws + ((pair == 0) ? XS_OFF : (pair == 1) ? XTG_OFF : XTD_OFF);
  int Lout = (pair < 2) ? 4096 : 1024;
  u16* xsb = (u16*)(ws + XSB_OFF);
  #pragma unroll
  for (int ct = 0; ct < 2; ++ct){
    int c = nh * 32 + ct * 16 + l15;
    f32x4 acc = {0.f, 0.f, 0.f, 0.f};
    #pragma unroll
    for (int kk = 0; kk < 4; ++kk){
      short8v Bf = *(const short8v*)(wf + (size_t)c * 128 + kk * 32 + ko * 8);
      acc = __builtin_amdgcn_mfma_f32_16x16x32_bf16(Af[kk], Bf, acc, 0, 0, 0);
      short8v Bb = *(const short8v*)(wb + (size_t)c * 128 + kk * 32 + ko * 8);
      acc = __builtin_amdgcn_mfma_f32_16x16x32_bf16(Ab[kk], Bb, acc, 0, 0, 0);
    }
    #pragma unroll
    for (int reg = 0; reg < 4; ++reg){
      int row = l0 + mt * 16 + ko * 4 + reg;
      float v = 0.5f * acc[reg];
      xo[((size_t)b * Lout + row) * 64 + c] = v;
      if (pair == 0) xsb[((size_t)b * 4096 + row) * 64 + c] = f2bu(v);
    }
  }
}

// ---------------- k_convmfma (+per-block GN partial store; plain stores, no contention) ----------
template<int NTAP>
__global__ __launch_bounds__(256) void k_convmfma(const bf16* __restrict__ act,
        float* __restrict__ outf, bf16* __restrict__ outb,
        const bf16* __restrict__ wt, const bf16* __restrict__ bias,
        float* __restrict__ part){
  __shared__ float red[4][4];
  int wid = blockIdx.x * 4 + (threadIdx.x >> 6);
  int lane = threadIdx.x & 63;
  int nc = wid & 1;
  int pt = wid >> 1;
  int b = pt >> 8, py = (pt >> 2) & 63, x0 = (pt & 3) << 4;
  int l15 = lane & 15, ko = lane >> 4;
  f32x4 acc0 = {0.f, 0.f, 0.f, 0.f}, acc1 = {0.f, 0.f, 0.f, 0.f};
  const bf16* ab = act + ((size_t)b * 4096) * 64;
  #pragma unroll
  for (int tap = 0; tap < NTAP; ++tap){
    int dy = (NTAP == 9) ? (tap / 3 - 1) : 0;
    int dx = (NTAP == 9) ? (tap % 3 - 1) : 0;
    int y = py + dy;
    bool yok = (NTAP == 1) || ((unsigned)y < 64u);
    int xx = x0 + l15 + dx;
    bool vall = yok && ((NTAP == 1) || ((unsigned)xx < 64u));
    const bf16* arow = ab + ((size_t)(y * 64 + xx)) * 64;
    const bf16* wrow = wt + (size_t)tap * 4096;
    #pragma unroll
    for (int kk = 0; kk < 2; ++kk){
      int ci0 = kk * 32 + ko * 8;
      short8v a;
      if (vall) a = *(const short8v*)(arow + ci0); else a = zero8();
      short8v bw0 = *(const short8v*)(wrow + (size_t)(nc * 32 + l15) * 64 + ci0);
      short8v bw1 = *(const short8v*)(wrow + (size_t)(nc * 32 + 16 + l15) * 64 + ci0);
      acc0 = __builtin_amdgcn_mfma_f32_16x16x32_bf16(a, bw0, acc0, 0, 0, 0);
      acc1 = __builtin_amdgcn_mfma_f32_16x16x32_bf16(a, bw1, acc1, 0, 0, 0);
    }
  }
  float bs0 = b2f(bias[nc * 32 + l15]);
  float bs1 = b2f(bias[nc * 32 + 16 + l15]);
  float s1a = 0.f, s2a = 0.f, s1b = 0.f, s2b = 0.f;
  size_t obase = ((size_t)b * 4096 + py * 64 + x0 + (ko << 2)) * 64 + nc * 32;
  #pragma unroll
  for (int r = 0; r < 4; ++r){
    float v0 = acc0[r] + bs0, v1 = acc1[r] + bs1;
    s1a += v0; s2a += v0 * v0; s1b += v1; s2b += v1 * v1;
    if (outf){
      outf[obase + (size_t)r * 64 + l15] = v0;
      outf[obase + (size_t)r * 64 + 16 + l15] = v1;
    } else {
      outb[obase + (size_t)r * 64 + l15] = __float2bfloat16(v0);
      outb[obase + (size_t)r * 64 + 16 + l15] = __float2bfloat16(v1);
    }
  }
  #pragma unroll
  for (int off = 1; off < 64; off <<= 1){
    s1a += __shfl_xor(s1a, off, 64); s2a += __shfl_xor(s2a, off, 64);
    s1b += __shfl_xor(s1b, off, 64); s2b += __shfl_xor(s2b, off, 64);
  }
  int w = threadIdx.x >> 6;
  if (lane == 0){ red[w][0] = s1a; red[w][1] = s2a; red[w][2] = s1b; red[w][3] = s2b; }
  __syncthreads();
  if (part && threadIdx.x < 8){
    int g = threadIdx.x >> 1, sel = threadIdx.x & 1;
    int w0 = g >> 1;
    int col = ((g & 1) << 1) + sel;
    part[(size_t)blockIdx.x * 8 + threadIdx.x] = red[w0][col] + red[w0 + 2][col];
  }
}

// ---------------- k_gn_act: prologue-reduce partials, then elementwise GN(+res)+gelu -------------
__global__ __launch_bounds__(256) void k_gn_act(const float* __restrict__ in, const float* __restrict__ res,
        bf16* __restrict__ outb, const float* __restrict__ part,
        const bf16* __restrict__ gw, const bf16* __restrict__ gb, int add_res){
  __shared__ float st8[8];
  int tid = threadIdx.x;
  int t = blockIdx.x * 256 + tid;
  int b = blockIdx.x >> 8;
  {
    int j = tid & 31, f = tid >> 5;
    float v = 0.f;
    #pragma unroll
    for (int k = 0; k < 4; ++k)
      v += part[(size_t)(b * 128 + j * 4 + k) * 8 + f];
    #pragma unroll
    for (int off = 16; off; off >>= 1) v += __shfl_down(v, off, 32);
    if (j == 0) st8[f] = v;
  }
  __syncthreads();
  int cq = t & 15, px = (t >> 4) & 4095;
  int c0 = cq * 4, g = cq >> 2;
  float mean = st8[g * 2] * (1.f / 65536.f);
  float rs = rsqrtf(st8[g * 2 + 1] * (1.f / 65536.f) - mean * mean + 1e-5f);
  size_t idx = ((size_t)b * 4096 + px) * 64 + c0;
  float4 f4 = *(const float4*)(in + idx);
  float vv[4] = {f4.x, f4.y, f4.z, f4.w};
  float rr[4] = {0.f, 0.f, 0.f, 0.f};
  if (add_res){ float4 r4 = *(const float4*)(res + idx); rr[0]=r4.x; rr[1]=r4.y; rr[2]=r4.z; rr[3]=r4.w; }
  u16 o[4];
  #pragma unroll
  for (int j = 0; j < 4; ++j){
    float v = (vv[j] - mean) * rs * b2f(gw[c0 + j]) + b2f(gb[c0 + j]);
    v += rr[j];
    o[j] = f2bu(gelu_f(v));
  }
  u32 lo = (u32)o[0] | ((u32)o[1] << 16);
  u32 hi = (u32)o[2] | ((u32)o[3] << 16);
  *(uint2*)((u16*)outb + idx) = make_uint2(lo, hi);
}

// ---------------- k_dwgelu ----------------
__global__ __launch_bounds__(256) void k_dwgelu(const bf16* __restrict__ in, bf16* __restrict__ out,
        const bf16* __restrict__ w, const bf16* __restrict__ bias){
  int id = blockIdx.x * 256 + threadIdx.x;
  int oc8 = id & 7, px = (id >> 3) & 4095, b = id >> 15;
  int py = px >> 6, pxx = px & 63;
  float wv[8][9];
  #pragma unroll
  for (int j = 0; j < 8; ++j)
    #pragma unroll
    for (int tp = 0; tp < 9; ++tp) wv[j][tp] = b2f(w[(oc8 * 8 + j) * 9 + tp]);
  float acc[8];
  #pragma unroll
  for (int j = 0; j < 8; ++j) acc[j] = b2f(bias[oc8 * 8 + j]);
  const bf16* inb = in + ((size_t)b * 4096) * 64;
  #pragma unroll
  for (int dy = 0; dy < 3; ++dy){
    int y = py + dy - 1;
    if ((unsigned)y >= 64u) continue;
    #pragma unroll
    for (int dx = 0; dx < 3; ++dx){
      int x = pxx + dx - 1;
      if ((unsigned)x >= 64u) continue;
      short8v iv = *(const short8v*)(inb + ((size_t)(y * 64 + x)) * 64 + oc8 * 8);
      #pragma unroll
      for (int j = 0; j < 8; ++j)
        acc[j] = fmaf(bits2f((u16)iv[j]), wv[j][dy * 3 + dx], acc[j]);
    }
  }
  u32 pk[4];
  #pragma unroll
  for (int k = 0; k < 4; ++k){
    u16 a0 = f2bu(gelu_f(acc[2 * k]));
    u16 a1 = f2bu(gelu_f(acc[2 * k + 1]));
    pk[k] = (u32)a0 | ((u32)a1 << 16);
  }
  *(uint4*)((u16*)out + ((size_t)b * 4096 + px) * 64 + oc8 * 8) = make_uint4(pk[0], pk[1], pk[2], pk[3]);
}

// ---------------- k_final: prologue-reduce partials, then fuse + upsample + sum -------------------
__global__ __launch_bounds__(256) void k_final(const float* __restrict__ ws, void* __restrict__ outp,
        const bf16* __restrict__ gw, const bf16* __restrict__ gb){
  __shared__ float st8[8];
  int flag = *(const int*)(ws + FLAG_OFF);
  int bid = blockIdx.x;
  int b = bid >> 6, py = bid & 63;
  int t = threadIdx.x;
  {
    const float* part = ws + PART_OFF + 3 * 2048;
    int j = t & 31, f = t >> 5;
    float v = 0.f;
    #pragma unroll
    for (int k = 0; k < 4; ++k)
      v += part[(size_t)(b * 128 + j * 4 + k) * 8 + f];
    #pragma unroll
    for (int off = 16; off; off >>= 1) v += __shfl_down(v, off, 32);
    if (j == 0) st8[f] = v;
  }
  __syncthreads();
  int c = t & 63, pxg = t >> 6;
  int g = c >> 4;
  float mean = st8[g * 2] * (1.f / 65536.f);
  float rs = rsqrtf(st8[g * 2 + 1] * (1.f / 65536.f) - mean * mean + 1e-5f);
  float gwv = b2f(gw[c]), gbv = b2f(gb[c]);
  const float* CV1 = ws + CV1_OFF;
  const bf16* PWB = (const bf16*)(ws + PWB_OFF);
  const float* XS = ws + XS_OFF;
  const float* XTG = ws + XTG_OFF;
  const float* XTD = ws + XTD_OFF + ((size_t)b * 1024) * 64;
  float sy = 0.5f * py - 0.25f;
  float fly = floorf(sy); float fy = sy - fly;
  int iy0 = max((int)fly, 0), iy1 = min((int)fly + 1, 31);
  float of[16];
  #pragma unroll
  for (int i = 0; i < 16; ++i){
    int px = pxg * 16 + i;
    size_t idx = ((size_t)b * 4096 + py * 64 + px) * 64 + c;
    float gn = (CV1[idx] - mean) * rs * gwv + gbv;
    float xl = gelu_f(b2f(PWB[idx]) + gn);
    float sx = 0.5f * px - 0.25f;
    float flx = floorf(sx); float fx = sx - flx;
    int ix0 = max((int)flx, 0), ix1 = min((int)flx + 1, 31);
    float v00 = XTD[(size_t)(iy0 * 32 + ix0) * 64 + c], v01 = XTD[(size_t)(iy0 * 32 + ix1) * 64 + c];
    float v10 = XTD[(size_t)(iy1 * 32 + ix0) * 64 + c], v11 = XTD[(size_t)(iy1 * 32 + ix1) * 64 + c];
    float tdv = (1.f - fy) * ((1.f - fx) * v00 + fx * v01) + fy * ((1.f - fx) * v10 + fx * v11);
    of[i] = XS[idx] + xl + 0.5f * XTG[idx] + 0.5f * tdv;
  }
  size_t ob = ((size_t)(b * 64 + c)) * 4096 + py * 64 + pxg * 16;
  if (flag){
    float* o = (float*)outp + ob;
    #pragma unroll
    for (int k = 0; k < 4; ++k)
      *(float4*)(o + k * 4) = make_float4(of[k*4], of[k*4+1], of[k*4+2], of[k*4+3]);
  } else {
    u16* o = (u16*)outp + ob;
    u32 pk[8];
    #pragma unroll
    for (int k = 0; k < 8; ++k)
      pk[k] = (u32)f2bu(of[2*k]) | ((u32)f2bu(of[2*k+1]) << 16);
    *(uint4*)(o) = make_uint4(pk[0], pk[1], pk[2], pk[3]);
    *(uint4*)(o + 8) = make_uint4(pk[4], pk[5], pk[6], pk[7]);
  }
}

// ---------------- launch ----------------
extern "C" void kernel_launch(void* const* d_in, const int* in_sizes, int n_in,
                              void* d_out, int out_size, void* d_ws, size_t ws_size,
                              hipStream_t stream) {
  float* ws = (float*)d_ws;
  bf16* XZ = (bf16*)(ws + XZ_OFF);
  bf16* prm = (bf16*)(ws + PRM_OFF);
  bf16* WT4 = (bf16*)(ws + WT4_OFF);
  bf16* XSB = (bf16*)(ws + XSB_OFF);
  bf16* A1B = (bf16*)(ws + A1B_OFF);
  bf16* A2B = (bf16*)(ws + A2B_OFF);
  bf16* PWBb = (bf16*)(ws + PWB_OFF);
  float* CV0 = ws + CV0_OFF;
  float* CV1 = ws + CV1_OFF;
  float* PART = ws + PART_OFF;

  const bf16* m_in_w   = prm + 0;
  const bf16* m_conv_w = prm + 98304;
  const bf16* m_conv_b = prm + 101376;
  const bf16* m_xproj  = prm + 102144;
  const bf16* m_dt_w   = prm + 129792;
  const bf16* m_dt_b   = prm + 132864;
  const bf16* m_A_log  = prm + 133632;
  const bf16* m_D      = prm + 145920;
  const bf16* m_out_w  = prm + 146688;
  const bf16* dw_w  = prm + 195840;
  const bf16* dw_b  = prm + 196416;
  const bf16* pw_w  = prm + 196480;
  const bf16* pw_b  = prm + 200576;
  const bf16* r1c1b = prm + 237504;
  const bf16* r1g1w = prm + 237568;
  const bf16* r1g1b = prm + 237632;
  const bf16* r1c2b = prm + 274560;
  const bf16* r1g2w = prm + 274624;
  const bf16* r1g2b = prm + 274688;
  const bf16* r2c1b = prm + 311616;
  const bf16* r2g1w = prm + 311680;
  const bf16* r2g1b = prm + 311744;
  const bf16* r2c2b = prm + 348672;
  const bf16* r2g2w = prm + 348736;
  const bf16* r2g2b = prm + 348800;

  P29 ptrs;
  for (int t = 0; t < 29; ++t) ptrs.p[t] = d_in[t + 1];

  k_detect<<<1, 256, 0, stream>>>(d_in[0], d_in[7], ws);
  k_setup<<<4499, 256, 0, stream>>>(ptrs, d_in[0], ws);
  k_inproj<<<1152, 256, 0, stream>>>(ws, XZ, m_in_w);
  k_front<<<1152, 256, 0, stream>>>(ws, m_xproj, m_dt_w, m_dt_b, m_conv_w, m_conv_b, m_A_log);
  k_scan2<<<96, 256, 0, stream>>>(ws);
  k_outproj<<<576, 256, 0, stream>>>(ws, m_out_w, m_A_log, m_D);

  // conv branch (NHWC); GN partials from conv epilogue, reduced in consumers
  k_convmfma<9><<<256, 256, 0, stream>>>(XSB, CV0, (bf16*)nullptr, WT4 + 0 * 36864, r1c1b, PART + 0 * 2048);
  k_gn_act<<<512, 256, 0, stream>>>(CV0, (const float*)nullptr, A1B, PART + 0 * 2048, r1g1w, r1g1b, 0);
  k_convmfma<9><<<256, 256, 0, stream>>>(A1B, CV1, (bf16*)nullptr, WT4 + 1 * 36864, r1c2b, PART + 1 * 2048);
  k_gn_act<<<512, 256, 0, stream>>>(CV1, ws + XS_OFF, A2B, PART + 1 * 2048, r1g2w, r1g2b, 1);
  k_dwgelu<<<256, 256, 0, stream>>>(A2B, A1B, dw_w, dw_b);
  k_convmfma<1><<<256, 256, 0, stream>>>(A1B, (float*)nullptr, PWBb, pw_w, pw_b, (float*)nullptr);
  k_convmfma<9><<<256, 256, 0, stream>>>(PWBb, CV0, (bf16*)nullptr, WT4 + 2 * 36864, r2c1b, PART + 2 * 2048);
  k_gn_act<<<512, 256, 0, stream>>>(CV0, (const float*)nullptr, A1B, PART + 2 * 2048, r2g1w, r2g1b, 0);
  k_convmfma<9><<<256, 256, 0, stream>>>(A1B, CV1, (bf16*)nullptr, WT4 + 3 * 36864, r2c2b, PART + 3 * 2048);
  k_final<<<128, 256, 0, stream>>>(ws, d_out, r2g2w, r2g2b);
}